// Round 1
// baseline (2238.468 us; speedup 1.0000x reference)
//
#include <hip/hip_runtime.h>
#include <math.h>

#define N_NODES  50000
#define N_EDGES  1000000
#define INV_AVG  0.05f   // N_NODES / N_EDGES

// ---------------- path tables ----------------
// PATHS in reference order (l1 outer, l2 mid, l3 inner):
__device__ __constant__ int c_L1[15]   = {0,0,0,1,1,1,1,1,1,2,2,2,2,2,2};
__device__ __constant__ int c_L2[15]   = {0,1,2,0,1,1,1,2,2,0,1,1,2,2,2};
__device__ __constant__ int c_L3[15]   = {0,1,2,1,0,1,2,1,2,2,1,2,0,1,2};
// flat offsets of each path's CG tensor ( (2l1+1)(2l2+1)(2l3+1) ), 16th = total
__device__ __constant__ int c_CGOFF[16] = {0,1,10,35,44,53,80,125,170,245,270,315,390,415,490,615};
// geo vector base offset per path (prefix sums of 2*l3+1), total 51
__device__ __constant__ int c_GEOB[15] = {0,1,4,9,12,13,16,21,24,29,34,37,42,43,46};
// alpha[l3] premultiplier per path: 1/sqrt(8*3) for l3=0, 1/sqrt(8*6) otherwise
__device__ __constant__ float c_ALPHA[15] = {
    0.20412414523193154f, 0.14433756729740643f, 0.14433756729740643f,
    0.14433756729740643f, 0.20412414523193154f, 0.14433756729740643f,
    0.14433756729740643f, 0.14433756729740643f, 0.14433756729740643f,
    0.14433756729740643f, 0.14433756729740643f, 0.14433756729740643f,
    0.20412414523193154f, 0.14433756729740643f, 0.14433756729740643f};
// (path, k) for each of the 51 geo slots
__device__ __constant__ int c_GEOP[51] = {
    0, 1,1,1, 2,2,2,2,2, 3,3,3, 4, 5,5,5, 6,6,6,6,6, 7,7,7,
    8,8,8,8,8, 9,9,9,9,9, 10,10,10, 11,11,11,11,11, 12, 13,13,13,
    14,14,14,14,14};
__device__ __constant__ int c_GEOK[51] = {
    0, 0,1,2, 0,1,2,3,4, 0,1,2, 0, 0,1,2, 0,1,2,3,4, 0,1,2,
    0,1,2,3,4, 0,1,2,3,4, 0,1,2, 0,1,2,3,4, 0, 0,1,2,
    0,1,2,3,4};

// ---------------- CG init kernel (ports reference _cg/_q/_real_cg) ----------------
struct cplxd { double re, im; };

__device__ inline double factd(int n) {
    double r = 1.0;
    for (int i = 2; i <= n; ++i) r *= (double)i;
    return r;
}

__device__ double cgc(int j1, int j2, int j3, int m1, int m2, int m3) {
    if (m1 + m2 != m3) return 0.0;
    double pre = sqrt((double)(2*j3+1) * factd(j3+j1-j2) * factd(j3-j1+j2) *
                      factd(j1+j2-j3) / factd(j1+j2+j3+1));
    pre *= sqrt(factd(j3+m3)*factd(j3-m3)*factd(j1-m1)*factd(j1+m1)*
                factd(j2-m2)*factd(j2+m2));
    double s = 0.0;
    for (int k = 0; k <= j1+j2-j3; ++k) {
        int d1 = j1+j2-j3-k, d2 = j1-m1-k, d3 = j2+m2-k,
            d4 = j3-j2+m1+k, d5 = j3-j1-m2+k;
        if (d1 < 0 || d2 < 0 || d3 < 0 || d4 < 0 || d5 < 0) continue;
        double term = 1.0 / (factd(k)*factd(d1)*factd(d2)*factd(d3)*factd(d4)*factd(d5));
        s += (k & 1) ? -term : term;
    }
    return pre * s;
}

// entry [a][i] of _q(l), including the (-1j)^l phase
__device__ inline cplxd qent(int l, int a, int i) {
    const double r2 = 0.70710678118654752440;
    double re = 0.0, im = 0.0;
    int m = a - l;
    if (m < 0) {
        if (i == l - m)      re = r2;     // col l+|m|
        else if (i == l + m) im = -r2;    // col l-|m|
    } else if (m == 0) {
        if (i == l) re = 1.0;
    } else {
        double s = (m & 1) ? -1.0 : 1.0;
        if (i == l + m)      re = s * r2;
        else if (i == l - m) im = s * r2;
    }
    if (l == 1)      { double t = re; re = im; im = -t; }  // * (-i)
    else if (l == 2) { re = -re; im = -im; }               // * (-1)
    cplxd q; q.re = re; q.im = im; return q;
}

__global__ void cg_init_kernel(float* __restrict__ cg_out) {
    __shared__ double s_re[615], s_im[615];
    __shared__ int s_flag[15];
    int t = threadIdx.x;
    int p = 0;
    if (t < 615) {
        p = 14;
        while (t < c_CGOFF[p]) --p;
        int l1 = c_L1[p], l2 = c_L2[p], l3 = c_L3[p];
        int d1 = 2*l1+1, d2 = 2*l2+1, d3 = 2*l3+1;
        int local = t - c_CGOFF[p];
        int i = local / (d2*d3);
        int r = local - i*d2*d3;
        int j = r / d3;
        int k = r - j*d3;
        double accre = 0.0, accim = 0.0;
        for (int a = 0; a < d1; ++a) {
            cplxd q1 = qent(l1, a, i);
            if (q1.re == 0.0 && q1.im == 0.0) continue;
            for (int b = 0; b < d2; ++b) {
                cplxd q2 = qent(l2, b, j);
                if (q2.re == 0.0 && q2.im == 0.0) continue;
                double t12r = q1.re*q2.re - q1.im*q2.im;
                double t12i = q1.re*q2.im + q1.im*q2.re;
                for (int c = 0; c < d3; ++c) {
                    cplxd q3 = qent(l3, c, k);
                    if (q3.re == 0.0 && q3.im == 0.0) continue;
                    int m1 = a-l1, m2 = b-l2, m3 = c-l3;
                    if (m1 + m2 != m3) continue;
                    double C = cgc(l1, l2, l3, m1, m2, m3);
                    if (C == 0.0) continue;
                    double cr = q3.re, ci = -q3.im;  // conj
                    accre += (t12r*cr - t12i*ci) * C;
                    accim += (t12r*ci + t12i*cr) * C;
                }
            }
        }
        s_re[t] = accre; s_im[t] = accim;
    }
    __syncthreads();
    if (t < 15) {
        double sre = 0.0, sim = 0.0;
        for (int q = c_CGOFF[t]; q < c_CGOFF[t+1]; ++q) {
            sre += fabs(s_re[q]); sim += fabs(s_im[q]);
        }
        s_flag[t] = (sre >= sim) ? 0 : 1;
    }
    __syncthreads();
    if (t < 615) {
        cg_out[t] = (float)(s_flag[p] ? s_im[t] : s_re[t]);
    }
}

// ---------------- per-node MLP: Ai = silu(emb[A] @ w1 + b1) @ w2 + b2 ----------------
__device__ inline float silu_f(float x) { return x / (1.0f + expf(-x)); }

__global__ __launch_bounds__(256) void node_kernel(
    const int* __restrict__ A, const float* __restrict__ emb_table,
    const float* __restrict__ w1, const float* __restrict__ b1,
    const float* __restrict__ w2, const float* __restrict__ b2,
    float* __restrict__ Ai)
{
    int v = blockIdx.x * 256 + threadIdx.x;
    if (v >= N_NODES) return;
    int a = A[v];
    float e[16];
#pragma unroll
    for (int i = 0; i < 16; ++i) e[i] = emb_table[a*16 + i];
    float acc[8];
#pragma unroll
    for (int c = 0; c < 8; ++c) acc[c] = b2[c];
    for (int j = 0; j < 64; ++j) {
        float t = b1[j];
#pragma unroll
        for (int i = 0; i < 16; ++i) t += e[i] * w1[i*64 + j];
        t = silu_f(t);
#pragma unroll
        for (int c = 0; c < 8; ++c) acc[c] += t * w2[j*8 + c];
    }
#pragma unroll
    for (int c = 0; c < 8; ++c) Ai[(long long)v*8 + c] = acc[c];
}

// ---------------- per-edge kernel: one wave per edge ----------------
__global__ __launch_bounds__(256) void edge_kernel(
    const float* __restrict__ pos,  const int* __restrict__ batch,
    const int* __restrict__ esrc,   const int* __restrict__ edst,
    const float* __restrict__ eshift, const float* __restrict__ cell,
    const float* __restrict__ fw1,  const float* __restrict__ fb1,
    const float* __restrict__ fw2,  const float* __restrict__ fb2,
    const float* __restrict__ fw3,  const float* __restrict__ fb3,
    const float* __restrict__ tpw,  const float* __restrict__ cg,
    const float* __restrict__ Ai,   float* __restrict__ out)
{
    __shared__ float s_w1[512];      // fc_w1 [8][64]
    __shared__ float s_w2[4096];     // fc_w2 [64][64]
    __shared__ float s_w3[960];      // fc_w3 [64][15]
    __shared__ float s_b1[64], s_b2[64], s_b3[16];
    __shared__ float s_tpw[1920];    // tp_weights [15][8][16]
    __shared__ float s_cg[616];      // CG tensors, 615 used
    __shared__ float u_Y[4][12];     // SH per wave (9 used)
    __shared__ float u_h1[4][64];
    __shared__ float u_h2[4][64];
    __shared__ float u_g[4][16];     // alpha * gates, 15 used
    __shared__ float u_Ai[4][8];
    __shared__ float u_geo[4][52];   // 51 used
    __shared__ float u_gch[4][240];  // gate*chan [15][16]

    const int tid = threadIdx.x;
    for (int i = tid; i < 512;  i += 256) s_w1[i]  = fw1[i];
    for (int i = tid; i < 4096; i += 256) s_w2[i]  = fw2[i];
    for (int i = tid; i < 960;  i += 256) s_w3[i]  = fw3[i];
    for (int i = tid; i < 1920; i += 256) s_tpw[i] = tpw[i];
    for (int i = tid; i < 615;  i += 256) s_cg[i]  = cg[i];
    if (tid < 64)  { s_b1[tid] = fb1[tid]; s_b2[tid] = fb2[tid]; }
    if (tid >= 64 && tid < 79) s_b3[tid - 64] = fb3[tid - 64];
    __syncthreads();

    const int wave = tid >> 6;
    const int lane = tid & 63;
    const long long stride = (long long)gridDim.x * 4;
    const long long base   = (long long)blockIdx.x * 4 + wave;
    const int iters = (int)((N_EDGES + stride - 1) / stride);

    for (int it = 0; it < iters; ++it) {
        long long e = base + (long long)it * stride;
        const bool active = (e < N_EDGES);
        int src = 0, dst = 0;
        float len = 0.0f, nx = 0.0f, ny = 0.0f, nz = 0.0f;
        if (active) {
            src = esrc[e]; dst = edst[e];
            int bb = batch[src];
            float s0 = eshift[e*3+0], s1 = eshift[e*3+1], s2 = eshift[e*3+2];
            const float* cl = cell + (long long)bb * 9;
            float shx = s0*cl[0] + s1*cl[3] + s2*cl[6];
            float shy = s0*cl[1] + s1*cl[4] + s2*cl[7];
            float shz = s0*cl[2] + s1*cl[5] + s2*cl[8];
            float vx = pos[dst*3+0] - pos[src*3+0] + shx;
            float vy = pos[dst*3+1] - pos[src*3+1] + shy;
            float vz = pos[dst*3+2] - pos[src*3+2] + shz;
            len = sqrtf(vx*vx + vy*vy + vz*vz);
            float inv = 1.0f / fmaxf(len, 1e-8f);
            nx = vx*inv; ny = vy*inv; nz = vz*inv;
        }
        // spherical harmonics -> LDS (lanes 0..8)
        {
            const float s3 = 1.7320508075688772f;
            const float s15 = 3.872983346207417f;
            const float s5 = 2.2360679774997896f;
            float yv = 0.0f;
            switch (lane) {
                case 0: yv = 1.0f; break;
                case 1: yv = s3*ny; break;
                case 2: yv = s3*nz; break;
                case 3: yv = s3*nx; break;
                case 4: yv = s15*nx*ny; break;
                case 5: yv = s15*ny*nz; break;
                case 6: yv = 0.5f*s5*(3.0f*nz*nz - 1.0f); break;
                case 7: yv = s15*nx*nz; break;
                case 8: yv = 0.5f*s15*(nx*nx - ny*ny); break;
                default: break;
            }
            if (lane < 9) u_Y[wave][lane] = yv;
        }
        // radial basis + first FC layer: lane j owns h1[j]
        {
            float embv[8];
#pragma unroll
            for (int b = 0; b < 8; ++b) {
                float ctr = (2.0f/9.0f) * (float)(b+1);
                float d = (len - ctr) * 4.5f;           // /step, step=2/9
                embv[b] = expf(-d*d) * 2.5253813613805274f;  // sqrt(8)/1.12
            }
            float t = s_b1[lane];
#pragma unroll
            for (int b = 0; b < 8; ++b) t += embv[b] * s_w1[b*64 + lane];
            u_h1[wave][lane] = silu_f(t);
        }
        __syncthreads();
        // second FC layer (64x64): lane j owns h2[j]
        {
            float t = s_b2[lane];
            const float* h1 = u_h1[wave];
#pragma unroll 8
            for (int i = 0; i < 64; ++i) t += h1[i] * s_w2[i*64 + lane];
            u_h2[wave][lane] = silu_f(t);
        }
        __syncthreads();
        // gates (lanes 0..14) with alpha folded in; Ai gather (lanes 32..39)
        if (lane < 15) {
            float g = s_b3[lane];
            const float* h2 = u_h2[wave];
            for (int i = 0; i < 64; ++i) g += h2[i] * s_w3[i*15 + lane];
            u_g[wave][lane] = g * c_ALPHA[lane];
        } else if (lane >= 32 && lane < 40 && active) {
            u_Ai[wave][lane - 32] = Ai[(long long)src*8 + (lane - 32)];
        }
        __syncthreads();
        // geo[51] (lanes 0..50)
        if (lane < 51) {
            int p = c_GEOP[lane], k = c_GEOK[lane];
            int l1 = c_L1[p], l2 = c_L2[p], l3 = c_L3[p];
            int d2 = 2*l2 + 1, d3 = 2*l3 + 1;
            const float* cgp = &s_cg[c_CGOFF[p]];
            const float* Ya = &u_Y[wave][l1*l1];
            const float* Yb = &u_Y[wave][l2*l2];
            float acc = 0.0f;
            for (int m = 0; m < 2*l1 + 1; ++m) {
                float ym = Ya[m];
                for (int n = 0; n < d2; ++n)
                    acc += ym * Yb[n] * cgp[(m*d2 + n)*d3 + k];
            }
            u_geo[wave][lane] = acc;
        }
        // gated channel weights [15][16] (all lanes, 4 reps)
#pragma unroll
        for (int rep = 0; rep < 4; ++rep) {
            int idx = lane + 64*rep;
            if (idx < 240) {
                int p = idx >> 4, c = idx & 15;
                float a = 0.0f;
#pragma unroll
                for (int m = 0; m < 8; ++m) a += u_Ai[wave][m] * s_tpw[p*128 + m*16 + c];
                u_gch[wave][idx] = a * u_g[wave][p];
            }
        }
        __syncthreads();
        // 144 outputs -> coalesced atomic row
        if (active) {
            float* orow = out + (long long)dst * 144;
            const float* gch = u_gch[wave];
            const float* geo = u_geo[wave];
#pragma unroll
            for (int rep = 0; rep < 3; ++rep) {
                int idx = lane + 64*rep;
                if (idx < 144) {
                    float v;
                    if (idx < 16) {
                        int c = idx;
                        v = gch[0*16+c]*geo[0] + gch[4*16+c]*geo[12] + gch[12*16+c]*geo[42];
                    } else if (idx < 64) {
                        int r = idx - 16; int c = r/3; int k = r - 3*c;
                        v = gch[1*16+c]*geo[1+k]  + gch[3*16+c]*geo[9+k]
                          + gch[5*16+c]*geo[13+k] + gch[7*16+c]*geo[21+k]
                          + gch[10*16+c]*geo[34+k] + gch[13*16+c]*geo[43+k];
                    } else {
                        int r = idx - 64; int c = r/5; int k = r - 5*c;
                        v = gch[2*16+c]*geo[4+k]  + gch[6*16+c]*geo[16+k]
                          + gch[8*16+c]*geo[24+k] + gch[9*16+c]*geo[29+k]
                          + gch[11*16+c]*geo[37+k] + gch[14*16+c]*geo[46+k];
                    }
                    atomicAdd(&orow[idx], v * INV_AVG);
                }
            }
        }
        __syncthreads();
    }
}

// ---------------- launch ----------------
extern "C" void kernel_launch(void* const* d_in, const int* in_sizes, int n_in,
                              void* d_out, int out_size, void* d_ws, size_t ws_size,
                              hipStream_t stream) {
    const float* pos       = (const float*)d_in[0];
    const int*   A         = (const int*)d_in[1];
    const int*   batch     = (const int*)d_in[2];
    const int*   esrc      = (const int*)d_in[3];
    const int*   edst      = (const int*)d_in[4];
    const float* eshift    = (const float*)d_in[5];
    const float* cell      = (const float*)d_in[6];
    const float* emb_table = (const float*)d_in[7];
    const float* mlp_w1    = (const float*)d_in[8];
    const float* mlp_b1    = (const float*)d_in[9];
    const float* mlp_w2    = (const float*)d_in[10];
    const float* mlp_b2    = (const float*)d_in[11];
    const float* fc_w1     = (const float*)d_in[12];
    const float* fc_b1     = (const float*)d_in[13];
    const float* fc_w2     = (const float*)d_in[14];
    const float* fc_b2     = (const float*)d_in[15];
    const float* fc_w3     = (const float*)d_in[16];
    const float* fc_b3     = (const float*)d_in[17];
    const float* tpw       = (const float*)d_in[18];
    float* out = (float*)d_out;

    float* ws_cg = (float*)d_ws;              // 615 floats
    float* ws_Ai = (float*)d_ws + 1024;       // 50000*8 floats

    hipMemsetAsync(d_out, 0, (size_t)out_size * sizeof(float), stream);
    hipLaunchKernelGGL(cg_init_kernel, dim3(1), dim3(640), 0, stream, ws_cg);
    hipLaunchKernelGGL(node_kernel, dim3((N_NODES + 255)/256), dim3(256), 0, stream,
                       A, emb_table, mlp_w1, mlp_b1, mlp_w2, mlp_b2, ws_Ai);
    hipLaunchKernelGGL(edge_kernel, dim3(1024), dim3(256), 0, stream,
                       pos, batch, esrc, edst, eshift, cell,
                       fc_w1, fc_b1, fc_w2, fc_b2, fc_w3, fc_b3,
                       tpw, ws_cg, ws_Ai, out);
}